// Round 18
// baseline (5000.633 us; speedup 1.0000x reference)
//
#include <hip/hip_runtime.h>
#include <math.h>

#define Bc 4
#define Nc 8192
#define NPOINTc 2048
#define NSAMPLEc 16
#define CINc 64
#define COUTc 128
#define FDIMc 67
#define NBUCK 128
#define EPSc 1e-5f

typedef unsigned long long u64;

// ---------------------------------------------------------------- K0: |xyz|^2 (f32, rn-chain)
__global__ void sq_norm_kernel(const float* __restrict__ xyz, float* __restrict__ sn) {
    int i = blockIdx.x * blockDim.x + threadIdx.x;
    if (i < Bc * Nc) {
        float x = xyz[i * 3], y = xyz[i * 3 + 1], z = xyz[i * 3 + 2];
        sn[i] = __fadd_rn(__fadd_rn(__fmul_rn(x, x), __fmul_rn(y, y)), __fmul_rn(z, z));
    }
}

// ---------------------------------------------------------------- DPP helpers (r14-proven pattern)
template <int CTRL>
__device__ __forceinline__ float dpp_maxf(float x) {
    const float o = __int_as_float(__builtin_amdgcn_update_dpp(
        __float_as_int(x), __float_as_int(x), CTRL, 0xF, 0xF, false));
    return fmaxf(x, o);
}
template <int CTRL>
__device__ __forceinline__ float dpp_minf(float x) {
    const float o = __int_as_float(__builtin_amdgcn_update_dpp(
        __float_as_int(x), __float_as_int(x), CTRL, 0xF, 0xF, false));
    return fminf(x, o);
}
template <int CTRL>
__device__ __forceinline__ unsigned dpp_minu(unsigned x) {
    const unsigned o = (unsigned)__builtin_amdgcn_update_dpp((int)x, (int)x, CTRL, 0xF, 0xF, false);
    return (o < x) ? o : x;
}
template <int CTRL>
__device__ __forceinline__ void kmax_dpp(u64& key) {
    const unsigned lo = (unsigned)key, hi = (unsigned)(key >> 32);
    const unsigned olo = (unsigned)__builtin_amdgcn_update_dpp((int)lo, (int)lo, CTRL, 0xF, 0xF, false);
    const unsigned ohi = (unsigned)__builtin_amdgcn_update_dpp((int)hi, (int)hi, CTRL, 0xF, 0xF, false);
    const u64 okey = ((u64)ohi << 32) | olo;
    key = (okey > key) ? okey : key;
}
__device__ __forceinline__ float wave_minf(float x) {
    x = dpp_minf<0x111>(x); x = dpp_minf<0x112>(x); x = dpp_minf<0x114>(x);
    x = dpp_minf<0x118>(x); x = dpp_minf<0x142>(x); x = dpp_minf<0x143>(x);
    return __int_as_float(__builtin_amdgcn_readlane(__float_as_int(x), 63));
}
__device__ __forceinline__ float wave_maxf(float x) {
    x = dpp_maxf<0x111>(x); x = dpp_maxf<0x112>(x); x = dpp_maxf<0x114>(x);
    x = dpp_maxf<0x118>(x); x = dpp_maxf<0x142>(x); x = dpp_maxf<0x143>(x);
    return __int_as_float(__builtin_amdgcn_readlane(__float_as_int(x), 63));
}

// ---------------------------------------------------------------- K1: FPS — wave-level Morton skip
// 512 thr, 8 waves. One-time 12-bit Morton counting sort (r15-proven machinery)
// gives each wave one octant (1024 contiguous sorted points) + a register bbox.
// Waves wid and wid+4 share a SIMD -> assign corner-opposite octants
// (ms = wid&4 ? wid^3 : wid) so active waves spread across SIMDs.
// Per iteration: WAVE-UNIFORM skip test lb(c,bbox)*(1-1e-5) >= v_prev (v_prev =
// wave's max D from phase-1, SGPR via readlane). Skip => all 16 min-updates are
// provably no-ops (d2 >= lb >= maxD >= D[k]) => D and the published key are
// unchanged => republish cached key. Active path = r15's full-lex tree +
// r14's two-phase DPP reduction (both proven). Output bit-identical: distances
// are placement-invariant bitwise; lex-argmax over (value, ORIGINAL idx).
__global__ __launch_bounds__(512) void fps_kernel(const float* __restrict__ xyz,
                                                  int* __restrict__ cent,
                                                  float* __restrict__ newxyz) {
    const int b = blockIdx.x;
    const float* base = xyz + (size_t)b * Nc * 3;
    const int t = threadIdx.x;
    const int lane = t & 63, wid = t >> 6;   // 8 waves

    __shared__ float P[Nc * 3];              // 96 KB original-order coords
    __shared__ u64   pk[2][8];
    __shared__ int   WIN[NPOINTc];           // 8 KB
    __shared__ int   hist[4096];             // 16 KB (16^3 Morton bins)
    __shared__ int   sidx[Nc];               // 32 KB sorted->original index
    __shared__ int   scanb[512];             // 2 KB

    for (int e = t; e < Nc * 3; e += 512) P[e] = base[e];
    for (int e = t; e < 4096; e += 512) hist[e] = 0;
    __syncthreads();

    // --- Morton codes + histogram (r15-proven)
    unsigned mc[16];
#pragma unroll
    for (int j = 0; j < 16; ++j) {
        const int n = t * 16 + j;
        const float x = P[n * 3], y = P[n * 3 + 1], z = P[n * 3 + 2];
        const unsigned xi = (unsigned)fminf(fmaxf(x * 16.f, 0.f), 15.f);
        const unsigned yi = (unsigned)fminf(fmaxf(y * 16.f, 0.f), 15.f);
        const unsigned zi = (unsigned)fminf(fmaxf(z * 16.f, 0.f), 15.f);
        unsigned c = 0;
#pragma unroll
        for (int bb = 0; bb < 4; ++bb)
            c |= (((xi >> bb) & 1u) << (3 * bb + 2)) | (((yi >> bb) & 1u) << (3 * bb + 1))
               | (((zi >> bb) & 1u) << (3 * bb));
        mc[j] = c;
        atomicAdd(&hist[c], 1);
    }
    __syncthreads();

    // --- exclusive scan (r15-proven)
    int loc[8]; int s = 0;
#pragma unroll
    for (int j = 0; j < 8; ++j) { loc[j] = s; s += hist[t * 8 + j]; }
    scanb[t] = s;
    __syncthreads();
    for (int off = 1; off < 512; off <<= 1) {
        const int add = (t >= off) ? scanb[t - off] : 0;
        __syncthreads();
        scanb[t] += add;
        __syncthreads();
    }
    const int base_off = scanb[t] - s;
#pragma unroll
    for (int j = 0; j < 8; ++j) hist[t * 8 + j] = base_off + loc[j];
    __syncthreads();

    // --- scatter (within-bin order arbitrary: selection is placement-invariant)
#pragma unroll
    for (int j = 0; j < 16; ++j) {
        const int slot = atomicAdd(&hist[mc[j]], 1);
        sidx[slot] = t * 16 + j;
    }
    __syncthreads();

    // --- load own slice (octant remap) + per-lane bbox
    const int ms = (wid & 4) ? (wid ^ 3) : wid;   // SIMD-mates get opposite octants
    float X[16], Y[16], Z[16], D[16]; int I[16];
    float bx0 = 1e30f, bx1 = -1e30f, by0 = 1e30f, by1 = -1e30f, bz0 = 1e30f, bz1 = -1e30f;
#pragma unroll
    for (int j = 0; j < 16; ++j) {
        const int si = sidx[ms * 1024 + lane * 16 + j];
        I[j] = si;
        const float x = P[si * 3], y = P[si * 3 + 1], z = P[si * 3 + 2];
        X[j] = x; Y[j] = y; Z[j] = z; D[j] = 1e10f;
        bx0 = fminf(bx0, x); bx1 = fmaxf(bx1, x);
        by0 = fminf(by0, y); by1 = fmaxf(by1, y);
        bz0 = fminf(bz0, z); bz1 = fmaxf(bz1, z);
    }
    // --- wave bbox (SGPR-uniform)
    const float wbx0 = wave_minf(bx0), wbx1 = wave_maxf(bx1);
    const float wby0 = wave_minf(by0), wby1 = wave_maxf(by1);
    const float wbz0 = wave_minf(bz0), wbz1 = wave_maxf(bz1);

    if (t == 0) WIN[0] = 0;
    __syncthreads();

    float cx = P[0], cy = P[1], cz = P[2];
    float vprev = 1e30f;                     // forces active at it=1
    u64 kw = 0;

    for (int it = 1; it < NPOINTc; ++it) {
        // --- wave-uniform skip test (conservative margin >> f32 chain error)
        const float gx = fmaxf(0.f, fmaxf(wbx0 - cx, cx - wbx1));
        const float gy = fmaxf(0.f, fmaxf(wby0 - cy, cy - wby1));
        const float gz = fmaxf(0.f, fmaxf(wbz0 - cz, cz - wbz1));
        const float lb = (gx * gx + gy * gy) + gz * gz;
        if (__fmul_rn(lb, 0.99999f) < vprev) {
            // --- ACTIVE: exact rn-chain distance update (reference semantics)
#pragma unroll
            for (int k = 0; k < 16; ++k) {
                const float dx = __fsub_rn(X[k], cx);
                const float dy = __fsub_rn(Y[k], cy);
                const float dz = __fsub_rn(Z[k], cz);
                const float d2 = __fadd_rn(__fadd_rn(__fmul_rn(dx, dx), __fmul_rn(dy, dy)),
                                           __fmul_rn(dz, dz));
                D[k] = fminf(D[k], d2);
            }
            // --- full-lex (val,idx) tree (r15-proven; indices arbitrary)
            float td0[8]; int ti0[8];
#pragma unroll
            for (int k = 0; k < 8; ++k) {
                const bool g = (D[2 * k + 1] > D[2 * k]) ||
                               (D[2 * k + 1] == D[2 * k] && I[2 * k + 1] < I[2 * k]);
                td0[k] = g ? D[2 * k + 1] : D[2 * k];
                ti0[k] = g ? I[2 * k + 1] : I[2 * k];
            }
            float td1[4]; int ti1[4];
#pragma unroll
            for (int k = 0; k < 4; ++k) {
                const bool g = (td1[0], (td0[2 * k + 1] > td0[2 * k]) ||
                               (td0[2 * k + 1] == td0[2 * k] && ti0[2 * k + 1] < ti0[2 * k]));
                td1[k] = g ? td0[2 * k + 1] : td0[2 * k];
                ti1[k] = g ? ti0[2 * k + 1] : ti0[2 * k];
            }
            float td2[2]; int ti2[2];
#pragma unroll
            for (int k = 0; k < 2; ++k) {
                const bool g = (td1[2 * k + 1] > td1[2 * k]) ||
                               (td1[2 * k + 1] == td1[2 * k] && ti1[2 * k + 1] < ti1[2 * k]);
                td2[k] = g ? td1[2 * k + 1] : td1[2 * k];
                ti2[k] = g ? ti1[2 * k + 1] : ti1[2 * k];
            }
            const bool gf = (td2[1] > td2[0]) || (td2[1] == td2[0] && ti2[1] < ti2[0]);
            const float bd = gf ? td2[1] : td2[0];
            const int   bi = gf ? ti2[1] : ti2[0];

            // --- phase 1: wave value-max -> SGPR
            const float v = wave_maxf(bd);
            // --- phase 2: lowest original index among value-ties
            unsigned cand = (bd == v) ? (unsigned)bi : 0xffffffffu;
            cand = dpp_minu<0x111>(cand);
            cand = dpp_minu<0x112>(cand);
            cand = dpp_minu<0x114>(cand);
            cand = dpp_minu<0x118>(cand);
            cand = dpp_minu<0x142>(cand);
            cand = dpp_minu<0x143>(cand);
            const unsigned candw = (unsigned)__builtin_amdgcn_readlane((int)cand, 63);

            vprev = v;
            kw = ((u64)__float_as_uint(v) << 32) | (unsigned)(~candw);
        }
        // --- SKIPPED waves republish the cached key (D unchanged => key unchanged)
        const int par = it & 1;
        if (lane == 63) pk[par][wid] = kw;
        __syncthreads();                     // drains lgkmcnt only (no VMEM in loop)

        // --- cross-wave: 8 partials, 3 u64 DPP steps -> lane 7 (r14-proven)
        u64 k8 = pk[par][lane & 7];
        if (lane >= 8) k8 = 0;
        kmax_dpp<0x111>(k8);
        kmax_dpp<0x112>(k8);
        kmax_dpp<0x114>(k8);
        const unsigned lo7 = (unsigned)__builtin_amdgcn_readlane((int)(unsigned)k8, 7);
        const int riv = (int)~lo7;

        cx = P[riv * 3 + 0]; cy = P[riv * 3 + 1]; cz = P[riv * 3 + 2];
        if (t == 0) WIN[it] = riv;
    }
    __syncthreads();

    for (int e = t; e < NPOINTc; e += 512) {
        const int wv2 = WIN[e];
        cent[b * NPOINTc + e] = wv2;
        float* o = newxyz + ((size_t)b * NPOINTc + e) * 3;
        o[0] = P[wv2 * 3 + 0]; o[1] = P[wv2 * 3 + 1]; o[2] = P[wv2 * 3 + 2];
    }
}

// ---------------------------------------------------------------- K2: KNN — DPP merge, padded LDS (r17)
__global__ __launch_bounds__(64) void knn_kernel(const float* __restrict__ xyz,
                                                 const float* __restrict__ sn,
                                                 const int* __restrict__ cent,
                                                 int* __restrict__ knn) {
    const int g = blockIdx.x;                // b*NPOINT + m
    const int b = g >> 11;
    const int lane = threadIdx.x;
    const float* base = xyz + (size_t)b * Nc * 3;
    const float* snb = sn + (size_t)b * Nc;

    const int cm = cent[g];
    const float mx = base[cm * 3 + 0];
    const float my = base[cm * 3 + 1];
    const float mz = base[cm * 3 + 2];
    const float s1 = snb[cm];

    float dls[16];
    int   ils[16];
#pragma unroll
    for (int j = 0; j < 16; ++j) { dls[j] = INFINITY; ils[j] = -1; }

    for (int jj = 0; jj < Nc / 64; ++jj) {
        const int n = lane + (jj << 6);
        const float x = base[n * 3 + 0];
        const float y = base[n * 3 + 1];
        const float z = base[n * 3 + 2];
        const float dot = fmaf(z, mz, fmaf(y, my, __fmul_rn(x, mx)));
        float d = __fadd_rn(__fadd_rn(__fmul_rn(-2.0f, dot), s1), snb[n]);
        d = fmaxf(d, 0.0f);
        if (d < dls[15]) {
            float cd = d; int ci = n;
#pragma unroll
            for (int j = 0; j < 16; ++j) {
                const bool less = cd < dls[j];
                const float td = less ? dls[j] : cd;
                const int   ti = less ? ils[j] : ci;
                dls[j] = less ? cd : dls[j];
                ils[j] = less ? ci : ils[j];
                cd = td; ci = ti;
            }
        }
    }

    __shared__ float ld[64][17];             // +1 pad: bank-conflict-free
    __shared__ int   li[64][17];
#pragma unroll
    for (int j = 0; j < 16; ++j) { ld[lane][j] = dls[j]; li[lane][j] = ils[j]; }

    int ptr = 0;
    int res = 0;
    int* out = knn + (size_t)g * NSAMPLEc;
    for (int r = 0; r < NSAMPLEc; ++r) {
        const float hd = ld[lane][ptr];
        const int   hi = li[lane][ptr];

        float vd = hd;
        vd = dpp_minf<0x111>(vd);
        vd = dpp_minf<0x112>(vd);
        vd = dpp_minf<0x114>(vd);
        vd = dpp_minf<0x118>(vd);
        vd = dpp_minf<0x142>(vd);
        vd = dpp_minf<0x143>(vd);
        const float v = __int_as_float(__builtin_amdgcn_readlane(__float_as_int(vd), 63));

        unsigned cand = (hd == v) ? (unsigned)hi : 0xffffffffu;
        cand = dpp_minu<0x111>(cand);
        cand = dpp_minu<0x112>(cand);
        cand = dpp_minu<0x114>(cand);
        cand = dpp_minu<0x118>(cand);
        cand = dpp_minu<0x142>(cand);
        cand = dpp_minu<0x143>(cand);
        const int win = (int)(unsigned)__builtin_amdgcn_readlane((int)cand, 63);

        if (hd == v && hi == win) ptr++;
        if (lane == r) res = win;
    }
    if (lane < NSAMPLEc) out[lane] = res;
}

// ---------------------------------------------------------------- staging helper (featT layout)
__device__ __forceinline__ void stage_featT(
        const float* __restrict__ px, const float* __restrict__ xyz,
        const float* __restrict__ newxyz, const int* __restrict__ knn,
        int g, int b, int t, float (*featT)[20], int* nidx, float* ctr) {
    if (t < 16) nidx[t] = knn[(size_t)g * NSAMPLEc + t];
    if (t < 3)  ctr[t] = newxyz[(size_t)g * 3 + t];
    __syncthreads();
    for (int e = t; e < 16 * FDIMc; e += 128) {
        const int s = e / FDIMc, i = e % FDIMc;
        float v;
        if (i < CINc) v = px[((size_t)b * Nc + nidx[s]) * CINc + i];
        else          v = __fsub_rn(xyz[((size_t)b * Nc + nidx[s]) * 3 + (i - CINc)], ctr[i - CINc]);
        featT[i][s] = v;
    }
    __syncthreads();
}

// ---------------------------------------------------------------- GEMM body
__device__ __forceinline__ void gemm_body(const float (*featT)[20], const float* __restrict__ W,
                                          float bc, int t, float* acc) {
#pragma unroll
    for (int r = 0; r < 16; ++r) acc[r] = bc;
    for (int i = 0; i < FDIMc; ++i) {
        const float w = W[i * COUTc + t];
        const float4* fr = (const float4*)featT[i];
        const float4 f0 = fr[0], f1 = fr[1], f2 = fr[2], f3 = fr[3];
        acc[0]  = fmaf(f0.x, w, acc[0]);  acc[1]  = fmaf(f0.y, w, acc[1]);
        acc[2]  = fmaf(f0.z, w, acc[2]);  acc[3]  = fmaf(f0.w, w, acc[3]);
        acc[4]  = fmaf(f1.x, w, acc[4]);  acc[5]  = fmaf(f1.y, w, acc[5]);
        acc[6]  = fmaf(f1.z, w, acc[6]);  acc[7]  = fmaf(f1.w, w, acc[7]);
        acc[8]  = fmaf(f2.x, w, acc[8]);  acc[9]  = fmaf(f2.y, w, acc[9]);
        acc[10] = fmaf(f2.z, w, acc[10]); acc[11] = fmaf(f2.w, w, acc[11]);
        acc[12] = fmaf(f3.x, w, acc[12]); acc[13] = fmaf(f3.y, w, acc[13]);
        acc[14] = fmaf(f3.z, w, acc[14]); acc[15] = fmaf(f3.w, w, acc[15]);
    }
}

// ---------------------------------------------------------------- K3: GEMM + BN stats + hmax -> out_px
__global__ __launch_bounds__(128) void gemm_stats_kernel(
        const float* __restrict__ px, const float* __restrict__ xyz,
        const float* __restrict__ newxyz, const int* __restrict__ knn,
        const float* __restrict__ W, const float* __restrict__ bias,
        float* __restrict__ bsum, float* __restrict__ bsq,
        float* __restrict__ hmax_out) {
    const int g = blockIdx.x;
    const int b = g >> 11;
    const int t = threadIdx.x;

    __shared__ __align__(16) float featT[FDIMc][20];
    __shared__ int nidx[16];
    __shared__ float ctr[3];
    stage_featT(px, xyz, newxyz, knn, g, b, t, featT, nidx, ctr);

    float acc[16];
    gemm_body(featT, W, bias[t], t, acc);

    float s = 0.f, q = 0.f, mx = acc[0];
#pragma unroll
    for (int r = 0; r < 16; ++r) { s += acc[r]; q += acc[r] * acc[r]; }
#pragma unroll
    for (int r = 1; r < 16; ++r) mx = fmaxf(mx, acc[r]);
    atomicAdd(&bsum[(g & (NBUCK - 1)) * COUTc + t], s);
    atomicAdd(&bsq [(g & (NBUCK - 1)) * COUTc + t], q);
    hmax_out[(size_t)g * COUTc + t] = mx;
}

// ---------------------------------------------------------------- K4: finalize stats (parallel)
__global__ __launch_bounds__(128) void stats_finalize_kernel(
        const float* __restrict__ bsum, const float* __restrict__ bsq,
        const float* __restrict__ gamma, const float* __restrict__ beta,
        float* __restrict__ scsh) {
    const int c = blockIdx.x;   // channel
    const int k = threadIdx.x;  // bucket
    __shared__ float sS[128], sQ[128];
    sS[k] = bsum[k * COUTc + c];
    sQ[k] = bsq[k * COUTc + c];
    __syncthreads();
    for (int s = 64; s > 0; s >>= 1) {
        if (k < s) { sS[k] += sS[k + s]; sQ[k] += sQ[k + s]; }
        __syncthreads();
    }
    if (k == 0) {
        const float cnt = (float)(Bc * NPOINTc * NSAMPLEc);
        const float mu = sS[0] / cnt;
        const float var = sQ[0] / cnt - mu * mu;
        const float sc = gamma[c] / sqrtf(var + EPSc);
        scsh[c] = sc;
        scsh[COUTc + c] = beta[c] - mu * sc;
        if (!(sc > 0.f)) atomicAdd(&scsh[2 * COUTc], 1.0f);   // slot pre-zeroed by memset
    }
}

// ---------------------------------------------------------------- K5: elementwise finalize (in place)
__global__ __launch_bounds__(256) void finalize_out_kernel(
        const float* __restrict__ scsh, float* __restrict__ out) {
    const int i = blockIdx.x * 256 + threadIdx.x;   // 8192*128 total
    const int c = i & (COUTc - 1);
    const float sc = scsh[c], sh = scsh[COUTc + c];
    out[i] = fmaxf(fmaf(out[i], sc, sh), 0.0f);     // out held hmax; exact for sc>0
}

// ---------------------------------------------------------------- K6: guard — recompute sc<=0 channels
__global__ __launch_bounds__(128) void guard_negsc_kernel(
        const float* __restrict__ px, const float* __restrict__ xyz,
        const float* __restrict__ newxyz, const int* __restrict__ knn,
        const float* __restrict__ W, const float* __restrict__ bias,
        const float* __restrict__ scsh, float* __restrict__ out) {
    if (scsh[2 * COUTc] == 0.0f) return;     // uniform early-exit (usual case)
    const int g = blockIdx.x;
    const int b = g >> 11;
    const int t = threadIdx.x;

    __shared__ __align__(16) float featT[FDIMc][20];
    __shared__ int nidx[16];
    __shared__ float ctr[3];
    stage_featT(px, xyz, newxyz, knn, g, b, t, featT, nidx, ctr);

    float acc[16];
    gemm_body(featT, W, bias[t], t, acc);

    const float sc = scsh[t], sh = scsh[COUTc + t];
    if (sc > 0.f) return;
    float m = -INFINITY;
#pragma unroll
    for (int r = 0; r < 16; ++r) m = fmaxf(m, fmaxf(fmaf(acc[r], sc, sh), 0.0f));
    out[(size_t)g * COUTc + t] = m;
}

// ---------------------------------------------------------------- launch
extern "C" void kernel_launch(void* const* d_in, const int* in_sizes, int n_in,
                              void* d_out, int out_size, void* d_ws, size_t ws_size,
                              hipStream_t stream) {
    const float* px    = (const float*)d_in[0];
    const float* xyz   = (const float*)d_in[1];
    const float* W     = (const float*)d_in[2];
    const float* bias  = (const float*)d_in[3];
    const float* gamma = (const float*)d_in[4];
    const float* beta  = (const float*)d_in[5];

    float* out_px = (float*)d_out;                                  // (B,NPOINT,128)
    float* out_nx = out_px + (size_t)Bc * NPOINTc * COUTc;          // (B,NPOINT,3)

    char* w = (char*)d_ws;
    int*   cent = (int*)w;    w += (size_t)Bc * NPOINTc * 4;
    float* sn   = (float*)w;  w += (size_t)Bc * Nc * 4;
    int*   knn  = (int*)w;    w += (size_t)Bc * NPOINTc * NSAMPLEc * 4;
    float* bsum = (float*)w;  w += (size_t)NBUCK * COUTc * 4;
    float* bsq  = (float*)w;  w += (size_t)NBUCK * COUTc * 4;
    float* scsh = (float*)w;  w += (2 * COUTc + 4) * 4;             // ~803 KB total (proven size)

    // zero bsum+bsq+scsh (contiguous) — includes the neg-sc flag slot
    hipMemsetAsync(bsum, 0, (size_t)NBUCK * COUTc * 4 * 2 + (2 * COUTc + 4) * 4, stream);

    sq_norm_kernel<<<(Bc * Nc + 255) / 256, 256, 0, stream>>>(xyz, sn);
    fps_kernel<<<Bc, 512, 0, stream>>>(xyz, cent, out_nx);
    knn_kernel<<<Bc * NPOINTc, 64, 0, stream>>>(xyz, sn, cent, knn);
    gemm_stats_kernel<<<Bc * NPOINTc, 128, 0, stream>>>(px, xyz, out_nx, knn, W, bias,
                                                        bsum, bsq, out_px);
    stats_finalize_kernel<<<COUTc, 128, 0, stream>>>(bsum, bsq, gamma, beta, scsh);
    finalize_out_kernel<<<(Bc * NPOINTc * COUTc) / 256, 256, 0, stream>>>(scsh, out_px);
    guard_negsc_kernel<<<Bc * NPOINTc, 128, 0, stream>>>(px, xyz, out_nx, knn, W, bias, scsh, out_px);
}

// Round 19
// 2696.607 us; speedup vs baseline: 1.8544x; 1.8544x over previous
//
#include <hip/hip_runtime.h>
#include <math.h>

#define Bc 4
#define Nc 8192
#define NPOINTc 2048
#define NSAMPLEc 16
#define CINc 64
#define COUTc 128
#define FDIMc 67
#define NBUCK 128
#define EPSc 1e-5f

typedef unsigned long long u64;

// ---------------------------------------------------------------- K0: |xyz|^2 (f32, rn-chain)
__global__ void sq_norm_kernel(const float* __restrict__ xyz, float* __restrict__ sn) {
    int i = blockIdx.x * blockDim.x + threadIdx.x;
    if (i < Bc * Nc) {
        float x = xyz[i * 3], y = xyz[i * 3 + 1], z = xyz[i * 3 + 2];
        sn[i] = __fadd_rn(__fadd_rn(__fmul_rn(x, x), __fmul_rn(y, y)), __fmul_rn(z, z));
    }
}

// ---------------------------------------------------------------- DPP helpers (r14-proven pattern)
template <int CTRL>
__device__ __forceinline__ float dpp_maxf(float x) {
    const float o = __int_as_float(__builtin_amdgcn_update_dpp(
        __float_as_int(x), __float_as_int(x), CTRL, 0xF, 0xF, false));
    return fmaxf(x, o);
}
template <int CTRL>
__device__ __forceinline__ float dpp_minf(float x) {
    const float o = __int_as_float(__builtin_amdgcn_update_dpp(
        __float_as_int(x), __float_as_int(x), CTRL, 0xF, 0xF, false));
    return fminf(x, o);
}
template <int CTRL>
__device__ __forceinline__ unsigned dpp_minu(unsigned x) {
    const unsigned o = (unsigned)__builtin_amdgcn_update_dpp((int)x, (int)x, CTRL, 0xF, 0xF, false);
    return (o < x) ? o : x;
}
template <int CTRL>
__device__ __forceinline__ void kmax_dpp(u64& key) {
    const unsigned lo = (unsigned)key, hi = (unsigned)(key >> 32);
    const unsigned olo = (unsigned)__builtin_amdgcn_update_dpp((int)lo, (int)lo, CTRL, 0xF, 0xF, false);
    const unsigned ohi = (unsigned)__builtin_amdgcn_update_dpp((int)hi, (int)hi, CTRL, 0xF, 0xF, false);
    const u64 okey = ((u64)ohi << 32) | olo;
    key = (okey > key) ? okey : key;
}

// ---------------------------------------------------------------- K1: FPS — EXACT r14/r17 (proven 2305 us)
__global__ __launch_bounds__(512) void fps_kernel(const float* __restrict__ xyz,
                                                  int* __restrict__ cent,
                                                  float* __restrict__ newxyz) {
    const int b = blockIdx.x;
    const float* base = xyz + (size_t)b * Nc * 3;
    const int t = threadIdx.x;
    const int lane = t & 63, wid = t >> 6;   // 8 waves

    __shared__ float P[Nc * 3];              // 96 KB point cache
    __shared__ u64   pk[2][8];               // parity-dbuf packed partials
    __shared__ int   WIN[NPOINTc];           // 8 KB winner buffer

    for (int e = t; e < Nc * 3; e += 512) P[e] = base[e];

    float X[16], Y[16], Z[16], D[16];
#pragma unroll
    for (int k = 0; k < 16; ++k) {
        const int n = t + (k << 9);
        X[k] = base[n * 3 + 0];
        Y[k] = base[n * 3 + 1];
        Z[k] = base[n * 3 + 2];
        D[k] = 1e10f;
    }
    if (t == 0) WIN[0] = 0;
    __syncthreads();

    float cx = P[0], cy = P[1], cz = P[2];

    for (int it = 1; it < NPOINTc; ++it) {
        // --- distance update: exact f32 rn-chain, no FMA (reference semantics)
#pragma unroll
        for (int k = 0; k < 16; ++k) {
            const float dx = __fsub_rn(X[k], cx);
            const float dy = __fsub_rn(Y[k], cy);
            const float dz = __fsub_rn(Z[k], cz);
            const float d2 = __fadd_rn(__fadd_rn(__fmul_rn(dx, dx), __fmul_rn(dy, dy)),
                                       __fmul_rn(dz, dz));
            D[k] = fminf(D[k], d2);
        }
        // --- per-thread 4-level (val,idx) tree; lowest-index tie-break
        float a0[8]; int x0[8];
#pragma unroll
        for (int k = 0; k < 8; ++k) {
            const bool g = D[2 * k + 1] > D[2 * k];
            a0[k] = g ? D[2 * k + 1] : D[2 * k];
            x0[k] = t + ((g ? (2 * k + 1) : (2 * k)) << 9);
        }
        float a1[4]; int x1[4];
#pragma unroll
        for (int k = 0; k < 4; ++k) {
            const bool g = a0[2 * k + 1] > a0[2 * k];
            a1[k] = g ? a0[2 * k + 1] : a0[2 * k];
            x1[k] = g ? x0[2 * k + 1] : x0[2 * k];
        }
        float a2[2]; int x2[2];
#pragma unroll
        for (int k = 0; k < 2; ++k) {
            const bool g = a1[2 * k + 1] > a1[2 * k];
            a2[k] = g ? a1[2 * k + 1] : a1[2 * k];
            x2[k] = g ? x1[2 * k + 1] : x1[2 * k];
        }
        const bool gf = a2[1] > a2[0];
        const float bd = gf ? a2[1] : a2[0];
        const int   bi = gf ? x2[1] : x2[0];

        // --- phase 1: wave value-max (fused DPP), complete in lane 63
        float wv = bd;
        wv = dpp_maxf<0x111>(wv);
        wv = dpp_maxf<0x112>(wv);
        wv = dpp_maxf<0x114>(wv);
        wv = dpp_maxf<0x118>(wv);
        wv = dpp_maxf<0x142>(wv);
        wv = dpp_maxf<0x143>(wv);
        const float v = __int_as_float(__builtin_amdgcn_readlane(__float_as_int(wv), 63));

        // --- phase 2: lowest index among value-ties
        unsigned cand = (bd == v) ? (unsigned)bi : 0xffffffffu;
        cand = dpp_minu<0x111>(cand);
        cand = dpp_minu<0x112>(cand);
        cand = dpp_minu<0x114>(cand);
        cand = dpp_minu<0x118>(cand);
        cand = dpp_minu<0x142>(cand);
        cand = dpp_minu<0x143>(cand);

        const int par = it & 1;
        if (lane == 63) pk[par][wid] = ((u64)__float_as_uint(v) << 32) | (unsigned)(~cand);
        __syncthreads();                     // drains lgkmcnt only (no VMEM in loop)

        // --- cross-wave: lanes 0-7 take the 8 partials, 3 u64 DPP steps -> lane 7
        u64 k8 = pk[par][lane & 7];
        if (lane >= 8) k8 = 0;
        kmax_dpp<0x111>(k8);
        kmax_dpp<0x112>(k8);
        kmax_dpp<0x114>(k8);
        const unsigned lo7 = (unsigned)__builtin_amdgcn_readlane((int)(unsigned)k8, 7);
        const int riv = (int)~lo7;

        cx = P[riv * 3 + 0]; cy = P[riv * 3 + 1]; cz = P[riv * 3 + 2];
        if (t == 0) WIN[it] = riv;
    }
    __syncthreads();

    for (int e = t; e < NPOINTc; e += 512) {
        const int wv2 = WIN[e];
        cent[b * NPOINTc + e] = wv2;
        float* o = newxyz + ((size_t)b * NPOINTc + e) * 3;
        o[0] = P[wv2 * 3 + 0]; o[1] = P[wv2 * 3 + 1]; o[2] = P[wv2 * 3 + 2];
    }
}

// ---------------------------------------------------------------- K2: KNN — DPP merge, padded LDS (r17)
__global__ __launch_bounds__(64) void knn_kernel(const float* __restrict__ xyz,
                                                 const float* __restrict__ sn,
                                                 const int* __restrict__ cent,
                                                 int* __restrict__ knn) {
    const int g = blockIdx.x;                // b*NPOINT + m
    const int b = g >> 11;
    const int lane = threadIdx.x;
    const float* base = xyz + (size_t)b * Nc * 3;
    const float* snb = sn + (size_t)b * Nc;

    const int cm = cent[g];
    const float mx = base[cm * 3 + 0];
    const float my = base[cm * 3 + 1];
    const float mz = base[cm * 3 + 2];
    const float s1 = snb[cm];

    float dls[16];
    int   ils[16];
#pragma unroll
    for (int j = 0; j < 16; ++j) { dls[j] = INFINITY; ils[j] = -1; }

    for (int jj = 0; jj < Nc / 64; ++jj) {
        const int n = lane + (jj << 6);
        const float x = base[n * 3 + 0];
        const float y = base[n * 3 + 1];
        const float z = base[n * 3 + 2];
        const float dot = fmaf(z, mz, fmaf(y, my, __fmul_rn(x, mx)));
        float d = __fadd_rn(__fadd_rn(__fmul_rn(-2.0f, dot), s1), snb[n]);
        d = fmaxf(d, 0.0f);
        if (d < dls[15]) {                   // strict: equal dist keeps existing lower idx
            float cd = d; int ci = n;
#pragma unroll
            for (int j = 0; j < 16; ++j) {
                const bool less = cd < dls[j];
                const float td = less ? dls[j] : cd;
                const int   ti = less ? ils[j] : ci;
                dls[j] = less ? cd : dls[j];
                ils[j] = less ? ci : ils[j];
                cd = td; ci = ti;
            }
        }
    }

    __shared__ float ld[64][17];             // +1 pad: bank-conflict-free
    __shared__ int   li[64][17];
#pragma unroll
    for (int j = 0; j < 16; ++j) { ld[lane][j] = dls[j]; li[lane][j] = ils[j]; }

    int ptr = 0;
    int res = 0;
    int* out = knn + (size_t)g * NSAMPLEc;
    for (int r = 0; r < NSAMPLEc; ++r) {
        const float hd = ld[lane][ptr];
        const int   hi = li[lane][ptr];

        float vd = hd;
        vd = dpp_minf<0x111>(vd);
        vd = dpp_minf<0x112>(vd);
        vd = dpp_minf<0x114>(vd);
        vd = dpp_minf<0x118>(vd);
        vd = dpp_minf<0x142>(vd);
        vd = dpp_minf<0x143>(vd);
        const float v = __int_as_float(__builtin_amdgcn_readlane(__float_as_int(vd), 63));

        unsigned cand = (hd == v) ? (unsigned)hi : 0xffffffffu;
        cand = dpp_minu<0x111>(cand);
        cand = dpp_minu<0x112>(cand);
        cand = dpp_minu<0x114>(cand);
        cand = dpp_minu<0x118>(cand);
        cand = dpp_minu<0x142>(cand);
        cand = dpp_minu<0x143>(cand);
        const int win = (int)(unsigned)__builtin_amdgcn_readlane((int)cand, 63);

        if (hd == v && hi == win) ptr++;
        if (lane == r) res = win;
    }
    if (lane < NSAMPLEc) out[lane] = res;
}

// ---------------------------------------------------------------- staging helper (featT layout)
__device__ __forceinline__ void stage_featT(
        const float* __restrict__ px, const float* __restrict__ xyz,
        const float* __restrict__ newxyz, const int* __restrict__ knn,
        int g, int b, int t, float (*featT)[20], int* nidx, float* ctr) {
    if (t < 16) nidx[t] = knn[(size_t)g * NSAMPLEc + t];
    if (t < 3)  ctr[t] = newxyz[(size_t)g * 3 + t];
    __syncthreads();
    for (int e = t; e < 16 * FDIMc; e += 128) {
        const int s = e / FDIMc, i = e % FDIMc;
        float v;
        if (i < CINc) v = px[((size_t)b * Nc + nidx[s]) * CINc + i];
        else          v = __fsub_rn(xyz[((size_t)b * Nc + nidx[s]) * 3 + (i - CINc)], ctr[i - CINc]);
        featT[i][s] = v;
    }
    __syncthreads();
}

// ---------------------------------------------------------------- GEMM body
__device__ __forceinline__ void gemm_body(const float (*featT)[20], const float* __restrict__ W,
                                          float bc, int t, float* acc) {
#pragma unroll
    for (int r = 0; r < 16; ++r) acc[r] = bc;
    for (int i = 0; i < FDIMc; ++i) {
        const float w = W[i * COUTc + t];
        const float4* fr = (const float4*)featT[i];
        const float4 f0 = fr[0], f1 = fr[1], f2 = fr[2], f3 = fr[3];
        acc[0]  = fmaf(f0.x, w, acc[0]);  acc[1]  = fmaf(f0.y, w, acc[1]);
        acc[2]  = fmaf(f0.z, w, acc[2]);  acc[3]  = fmaf(f0.w, w, acc[3]);
        acc[4]  = fmaf(f1.x, w, acc[4]);  acc[5]  = fmaf(f1.y, w, acc[5]);
        acc[6]  = fmaf(f1.z, w, acc[6]);  acc[7]  = fmaf(f1.w, w, acc[7]);
        acc[8]  = fmaf(f2.x, w, acc[8]);  acc[9]  = fmaf(f2.y, w, acc[9]);
        acc[10] = fmaf(f2.z, w, acc[10]); acc[11] = fmaf(f2.w, w, acc[11]);
        acc[12] = fmaf(f3.x, w, acc[12]); acc[13] = fmaf(f3.y, w, acc[13]);
        acc[14] = fmaf(f3.z, w, acc[14]); acc[15] = fmaf(f3.w, w, acc[15]);
    }
}

// ---------------------------------------------------------------- K3: GEMM + BN stats + hmax -> out_px
__global__ __launch_bounds__(128) void gemm_stats_kernel(
        const float* __restrict__ px, const float* __restrict__ xyz,
        const float* __restrict__ newxyz, const int* __restrict__ knn,
        const float* __restrict__ W, const float* __restrict__ bias,
        float* __restrict__ bsum, float* __restrict__ bsq,
        float* __restrict__ hmax_out) {
    const int g = blockIdx.x;
    const int b = g >> 11;
    const int t = threadIdx.x;

    __shared__ __align__(16) float featT[FDIMc][20];
    __shared__ int nidx[16];
    __shared__ float ctr[3];
    stage_featT(px, xyz, newxyz, knn, g, b, t, featT, nidx, ctr);

    float acc[16];
    gemm_body(featT, W, bias[t], t, acc);

    float s = 0.f, q = 0.f, mx = acc[0];
#pragma unroll
    for (int r = 0; r < 16; ++r) { s += acc[r]; q += acc[r] * acc[r]; }
#pragma unroll
    for (int r = 1; r < 16; ++r) mx = fmaxf(mx, acc[r]);
    atomicAdd(&bsum[(g & (NBUCK - 1)) * COUTc + t], s);
    atomicAdd(&bsq [(g & (NBUCK - 1)) * COUTc + t], q);
    hmax_out[(size_t)g * COUTc + t] = mx;
}

// ---------------------------------------------------------------- K4: finalize stats (parallel)
__global__ __launch_bounds__(128) void stats_finalize_kernel(
        const float* __restrict__ bsum, const float* __restrict__ bsq,
        const float* __restrict__ gamma, const float* __restrict__ beta,
        float* __restrict__ scsh) {
    const int c = blockIdx.x;   // channel
    const int k = threadIdx.x;  // bucket
    __shared__ float sS[128], sQ[128];
    sS[k] = bsum[k * COUTc + c];
    sQ[k] = bsq[k * COUTc + c];
    __syncthreads();
    for (int s = 64; s > 0; s >>= 1) {
        if (k < s) { sS[k] += sS[k + s]; sQ[k] += sQ[k + s]; }
        __syncthreads();
    }
    if (k == 0) {
        const float cnt = (float)(Bc * NPOINTc * NSAMPLEc);
        const float mu = sS[0] / cnt;
        const float var = sQ[0] / cnt - mu * mu;
        const float sc = gamma[c] / sqrtf(var + EPSc);
        scsh[c] = sc;
        scsh[COUTc + c] = beta[c] - mu * sc;
        if (!(sc > 0.f)) atomicAdd(&scsh[2 * COUTc], 1.0f);   // slot pre-zeroed by memset
    }
}

// ---------------------------------------------------------------- K5: elementwise finalize (in place)
__global__ __launch_bounds__(256) void finalize_out_kernel(
        const float* __restrict__ scsh, float* __restrict__ out) {
    const int i = blockIdx.x * 256 + threadIdx.x;   // 8192*128 total
    const int c = i & (COUTc - 1);
    const float sc = scsh[c], sh = scsh[COUTc + c];
    out[i] = fmaxf(fmaf(out[i], sc, sh), 0.0f);     // out held hmax; exact for sc>0
}

// ---------------------------------------------------------------- K6: guard — recompute sc<=0 channels
__global__ __launch_bounds__(128) void guard_negsc_kernel(
        const float* __restrict__ px, const float* __restrict__ xyz,
        const float* __restrict__ newxyz, const int* __restrict__ knn,
        const float* __restrict__ W, const float* __restrict__ bias,
        const float* __restrict__ scsh, float* __restrict__ out) {
    if (scsh[2 * COUTc] == 0.0f) return;     // uniform early-exit (usual case)
    const int g = blockIdx.x;
    const int b = g >> 11;
    const int t = threadIdx.x;

    __shared__ __align__(16) float featT[FDIMc][20];
    __shared__ int nidx[16];
    __shared__ float ctr[3];
    stage_featT(px, xyz, newxyz, knn, g, b, t, featT, nidx, ctr);

    float acc[16];
    gemm_body(featT, W, bias[t], t, acc);

    const float sc = scsh[t], sh = scsh[COUTc + t];
    if (sc > 0.f) return;
    float m = -INFINITY;
#pragma unroll
    for (int r = 0; r < 16; ++r) m = fmaxf(m, fmaxf(fmaf(acc[r], sc, sh), 0.0f));
    out[(size_t)g * COUTc + t] = m;
}

// ---------------------------------------------------------------- launch
extern "C" void kernel_launch(void* const* d_in, const int* in_sizes, int n_in,
                              void* d_out, int out_size, void* d_ws, size_t ws_size,
                              hipStream_t stream) {
    const float* px    = (const float*)d_in[0];
    const float* xyz   = (const float*)d_in[1];
    const float* W     = (const float*)d_in[2];
    const float* bias  = (const float*)d_in[3];
    const float* gamma = (const float*)d_in[4];
    const float* beta  = (const float*)d_in[5];

    float* out_px = (float*)d_out;                                  // (B,NPOINT,128)
    float* out_nx = out_px + (size_t)Bc * NPOINTc * COUTc;          // (B,NPOINT,3)

    char* w = (char*)d_ws;
    int*   cent = (int*)w;    w += (size_t)Bc * NPOINTc * 4;
    float* sn   = (float*)w;  w += (size_t)Bc * Nc * 4;
    int*   knn  = (int*)w;    w += (size_t)Bc * NPOINTc * NSAMPLEc * 4;
    float* bsum = (float*)w;  w += (size_t)NBUCK * COUTc * 4;
    float* bsq  = (float*)w;  w += (size_t)NBUCK * COUTc * 4;
    float* scsh = (float*)w;  w += (2 * COUTc + 4) * 4;             // ~803 KB total (proven size)

    // zero bsum+bsq+scsh (contiguous) — includes the neg-sc flag slot
    hipMemsetAsync(bsum, 0, (size_t)NBUCK * COUTc * 4 * 2 + (2 * COUTc + 4) * 4, stream);

    sq_norm_kernel<<<(Bc * Nc + 255) / 256, 256, 0, stream>>>(xyz, sn);
    fps_kernel<<<Bc, 512, 0, stream>>>(xyz, cent, out_nx);
    knn_kernel<<<Bc * NPOINTc, 64, 0, stream>>>(xyz, sn, cent, knn);
    gemm_stats_kernel<<<Bc * NPOINTc, 128, 0, stream>>>(px, xyz, out_nx, knn, W, bias,
                                                        bsum, bsq, out_px);
    stats_finalize_kernel<<<COUTc, 128, 0, stream>>>(bsum, bsq, gamma, beta, scsh);
    finalize_out_kernel<<<(Bc * NPOINTc * COUTc) / 256, 256, 0, stream>>>(scsh, out_px);
    guard_negsc_kernel<<<Bc * NPOINTc, 128, 0, stream>>>(px, xyz, out_nx, knn, W, bias, scsh, out_px);
}